// Round 3
// baseline (982.368 us; speedup 1.0000x reference)
//
#include <hip/hip_runtime.h>
#include <hip/hip_bf16.h>
#include <math.h>

#define C 128
#define H 4

// ---------------- CSR build ----------------
// edge_index arrives as int32 (harness converts integer inputs to int32).

__global__ void hist_kernel(const int* __restrict__ ei, int E, int N,
                            int* __restrict__ count) {
    int total = E + N;
    for (int e = blockIdx.x * blockDim.x + threadIdx.x; e < total;
         e += gridDim.x * blockDim.x) {
        int d = (e < E) ? ei[E + e] : (e - E);
        if ((unsigned)d < (unsigned)N) atomicAdd(&count[d], 1);
    }
}

__global__ __launch_bounds__(1024) void scan_kernel(const int* __restrict__ count,
                                                    int* __restrict__ offs,
                                                    int* __restrict__ cursor, int N) {
    const int T = 1024;
    int tid = threadIdx.x;
    int CH = (N + T - 1) / T;
    int base = tid * CH;
    int s = 0;
    for (int j = 0; j < CH; ++j) {
        int i = base + j;
        if (i < N) s += count[i];
    }
    __shared__ int part[T];
    part[tid] = s;
    __syncthreads();
    for (int off = 1; off < T; off <<= 1) {
        int v = (tid >= off) ? part[tid - off] : 0;
        __syncthreads();
        part[tid] += v;
        __syncthreads();
    }
    int run = (tid == 0) ? 0 : part[tid - 1];
    for (int j = 0; j < CH; ++j) {
        int i = base + j;
        if (i < N) {
            offs[i] = run;
            cursor[i] = run;
            run += count[i];
        }
    }
    if (tid == T - 1) offs[N] = part[T - 1];
}

__global__ void scatter_kernel(const int* __restrict__ ei, int E, int N,
                               int* __restrict__ cursor, int* __restrict__ srcs) {
    int total = E + N;
    for (int e = blockIdx.x * blockDim.x + threadIdx.x; e < total;
         e += gridDim.x * blockDim.x) {
        int sNode, d;
        if (e < E) { sNode = ei[e]; d = ei[E + e]; }
        else       { sNode = e - E; d = sNode; }
        if ((unsigned)d < (unsigned)N && (unsigned)sNode < (unsigned)N) {
            int pos = atomicAdd(&cursor[d], 1);
            srcs[pos] = sNode;
        }
    }
}

// ---------------- W@a vectors: vs[h][i] = sum_o W[h][i][o]*a_src[h][o] ----------------

__global__ __launch_bounds__(128) void wvec_kernel(const float* __restrict__ W,
                                                   const float* __restrict__ av_s,
                                                   const float* __restrict__ av_d,
                                                   float* __restrict__ vs,
                                                   float* __restrict__ vd) {
    int h = blockIdx.x;
    int i = threadIdx.x;
    const float* Wr = W + ((size_t)h * C + i) * C;
    float s = 0.f, d = 0.f;
    for (int o = 0; o < C; ++o) {
        float w = Wr[o];
        s += w * av_s[h * C + o];
        d += w * av_d[h * C + o];
    }
    vs[h * C + i] = s;
    vd[h * C + i] = d;
}

// ---------------- attention scalars: als/ald [N][H] ----------------

__global__ __launch_bounds__(256) void al_kernel(const float* __restrict__ in,
                                                 const float* __restrict__ vs,
                                                 const float* __restrict__ vd,
                                                 float* __restrict__ als,
                                                 float* __restrict__ ald, int N) {
    int node = blockIdx.x * 4 + (threadIdx.x >> 6);
    int lane = threadIdx.x & 63;
    if (node >= N) return;
    float x0 = in[(size_t)node * C + lane];
    float x1 = in[(size_t)node * C + 64 + lane];
    #pragma unroll
    for (int h = 0; h < H; ++h) {
        float ps = x0 * vs[h * C + lane] + x1 * vs[h * C + 64 + lane];
        float pd = x0 * vd[h * C + lane] + x1 * vd[h * C + 64 + lane];
        #pragma unroll
        for (int m = 32; m; m >>= 1) {
            ps += __shfl_xor(ps, m);
            pd += __shfl_xor(pd, m);
        }
        if (lane == 0) {
            als[node * H + h] = ps;
            ald[node * H + h] = pd;
        }
    }
}

// ---------------- per-dst softmax -> per-edge alpha[h][e] ----------------

__device__ __forceinline__ float lrelu(float x) { return x > 0.f ? x : 0.2f * x; }

__global__ __launch_bounds__(256) void alpha_kernel(const float* __restrict__ als,
                                                    const float* __restrict__ ald,
                                                    const int* __restrict__ offs,
                                                    const int* __restrict__ srcs,
                                                    float* __restrict__ alpha,
                                                    int N, int ET) {
    int node = blockIdx.x * 4 + (threadIdx.x >> 6);
    int lane = threadIdx.x & 63;
    if (node >= N) return;
    int beg = offs[node], end = offs[node + 1];
    float ad0 = ald[node * H + 0];
    float ad1 = ald[node * H + 1];
    float ad2 = ald[node * H + 2];
    float ad3 = ald[node * H + 3];

    float mx0 = -INFINITY, mx1 = -INFINITY, mx2 = -INFINITY, mx3 = -INFINITY;
    for (int i = beg + lane; i < end; i += 64) {
        int s = srcs[i];
        const float* ar = &als[s * H];
        mx0 = fmaxf(mx0, lrelu(ar[0] + ad0));
        mx1 = fmaxf(mx1, lrelu(ar[1] + ad1));
        mx2 = fmaxf(mx2, lrelu(ar[2] + ad2));
        mx3 = fmaxf(mx3, lrelu(ar[3] + ad3));
    }
    #pragma unroll
    for (int m = 32; m; m >>= 1) {
        mx0 = fmaxf(mx0, __shfl_xor(mx0, m));
        mx1 = fmaxf(mx1, __shfl_xor(mx1, m));
        mx2 = fmaxf(mx2, __shfl_xor(mx2, m));
        mx3 = fmaxf(mx3, __shfl_xor(mx3, m));
    }
    float dn0 = 0.f, dn1 = 0.f, dn2 = 0.f, dn3 = 0.f;
    for (int i = beg + lane; i < end; i += 64) {
        int s = srcs[i];
        const float* ar = &als[s * H];
        dn0 += expf(lrelu(ar[0] + ad0) - mx0);
        dn1 += expf(lrelu(ar[1] + ad1) - mx1);
        dn2 += expf(lrelu(ar[2] + ad2) - mx2);
        dn3 += expf(lrelu(ar[3] + ad3) - mx3);
    }
    #pragma unroll
    for (int m = 32; m; m >>= 1) {
        dn0 += __shfl_xor(dn0, m);
        dn1 += __shfl_xor(dn1, m);
        dn2 += __shfl_xor(dn2, m);
        dn3 += __shfl_xor(dn3, m);
    }
    float inv0 = 1.f / dn0, inv1 = 1.f / dn1, inv2 = 1.f / dn2, inv3 = 1.f / dn3;
    for (int i = beg + lane; i < end; i += 64) {
        int s = srcs[i];
        const float* ar = &als[s * H];
        alpha[0 * (size_t)ET + i] = expf(lrelu(ar[0] + ad0) - mx0) * inv0;
        alpha[1 * (size_t)ET + i] = expf(lrelu(ar[1] + ad1) - mx1) * inv1;
        alpha[2 * (size_t)ET + i] = expf(lrelu(ar[2] + ad2) - mx2) * inv2;
        alpha[3 * (size_t)ET + i] = expf(lrelu(ar[3] + ad3) - mx3) * inv3;
    }
}

// ---------------- GEMM (one head): XH[n][c] = sum_k X[n][k] * Wh[k][c] ----------------

__global__ __launch_bounds__(256) void gemm_kernel(const float* __restrict__ X,
                                                   const float* __restrict__ Wh,
                                                   float* __restrict__ XH, int N) {
    __shared__ float As[16][65];
    __shared__ float Bs[16][64];
    int tid = threadIdx.x;
    int tx = tid & 15, ty = tid >> 4;
    int rowBase = blockIdx.x * 64;
    int colBase = blockIdx.y * 64;
    float acc[4][4] = {};
    for (int k0 = 0; k0 < C; k0 += 16) {
        #pragma unroll
        for (int j = 0; j < 4; ++j) {
            int idx = j * 256 + tid;
            int kk = idx & 15, m = idx >> 4;
            int r = rowBase + m;
            As[kk][m] = (r < N) ? X[(size_t)r * C + k0 + kk] : 0.f;
        }
        #pragma unroll
        for (int j = 0; j < 4; ++j) {
            int idx = j * 256 + tid;
            int kk = idx >> 6, c = idx & 63;
            Bs[kk][c] = Wh[(size_t)(k0 + kk) * C + colBase + c];
        }
        __syncthreads();
        #pragma unroll
        for (int kk = 0; kk < 16; ++kk) {
            float a[4], b[4];
            #pragma unroll
            for (int i = 0; i < 4; ++i) a[i] = As[kk][ty * 4 + i];
            #pragma unroll
            for (int j = 0; j < 4; ++j) b[j] = Bs[kk][tx * 4 + j];
            #pragma unroll
            for (int i = 0; i < 4; ++i)
                #pragma unroll
                for (int j = 0; j < 4; ++j) acc[i][j] += a[i] * b[j];
        }
        __syncthreads();
    }
    #pragma unroll
    for (int i = 0; i < 4; ++i) {
        int r = rowBase + ty * 4 + i;
        if (r < N) {
            #pragma unroll
            for (int j = 0; j < 4; ++j) {
                XH[(size_t)r * C + colBase + tx * 4 + j] = acc[i][j];
            }
        }
    }
}

// ---------------- bias init ----------------

__global__ __launch_bounds__(256) void bias_kernel(float* __restrict__ out,
                                                   const float* __restrict__ b,
                                                   int total, int accum) {
    int i = blockIdx.x * blockDim.x + threadIdx.x;
    if (i < total) {
        float v = b[i & (C - 1)];
        if (accum) out[i] += v;
        else out[i] = v;
    }
}

// ---------------- aggregation (one head): out[n] += 0.25 * sum alpha*xh[src] ----------------

__global__ __launch_bounds__(256) void agg_kernel(const float* __restrict__ xh,
                                                  const float* __restrict__ alpha_h,
                                                  const int* __restrict__ offs,
                                                  const int* __restrict__ srcs,
                                                  float* __restrict__ out, int N) {
    int node = blockIdx.x * 4 + (threadIdx.x >> 6);
    int lane = threadIdx.x & 63;
    if (node >= N) return;
    int beg = offs[node], end = offs[node + 1];
    float acc0 = 0.f, acc1 = 0.f;
    for (int i = beg; i < end; ++i) {
        int s = srcs[i];
        float w = alpha_h[i];
        acc0 += w * xh[(size_t)s * C + lane];
        acc1 += w * xh[(size_t)s * C + 64 + lane];
    }
    out[(size_t)node * C + lane] += 0.25f * acc0;
    out[(size_t)node * C + 64 + lane] += 0.25f * acc1;
}

// ---------------- launch ----------------

extern "C" void kernel_launch(void* const* d_in, const int* in_sizes, int n_in,
                              void* d_out, int out_size, void* d_ws, size_t ws_size,
                              hipStream_t stream) {
    const float* x = (const float*)d_in[0];
    const int* ei = (const int*)d_in[1];   // int32 — harness converts integer inputs
    const float* Wl[3]  = {(const float*)d_in[2], (const float*)d_in[6], (const float*)d_in[10]};
    const float* asl[3] = {(const float*)d_in[3], (const float*)d_in[7], (const float*)d_in[11]};
    const float* adl[3] = {(const float*)d_in[4], (const float*)d_in[8], (const float*)d_in[12]};
    const float* bl[3]  = {(const float*)d_in[5], (const float*)d_in[9], (const float*)d_in[13]};

    int N = in_sizes[0] / C;   // 20000
    int E = in_sizes[1] / 2;   // 320000
    int ET = E + N;

    // workspace layout (bytes)
    size_t sz_h1    = (size_t)N * C * 4;
    size_t sz_xh    = (size_t)N * C * 4;
    size_t sz_als   = (size_t)N * H * 4;
    size_t sz_vbuf  = (size_t)2 * H * C * 4;
    size_t sz_count = (size_t)N * 4;
    size_t sz_offs  = (size_t)(N + 1) * 4;
    size_t sz_cur   = (size_t)N * 4;
    size_t sz_srcs  = (size_t)ET * 4;
    size_t sz_alpha = (size_t)H * ET * 4;
    size_t required = sz_h1 + sz_xh + 2 * sz_als + sz_vbuf + sz_count + sz_offs +
                      sz_cur + sz_srcs + sz_alpha;
    if (ws_size < required) return;  // clean absmax failure instead of OOB abort

    char* w = (char*)d_ws;
    float* h1 = (float*)w;    w += sz_h1;
    float* xh = (float*)w;    w += sz_xh;
    float* als = (float*)w;   w += sz_als;
    float* ald = (float*)w;   w += sz_als;
    float* vs = (float*)w;    w += sz_vbuf / 2;
    float* vd = (float*)w;    w += sz_vbuf / 2;
    int* count = (int*)w;     w += sz_count;
    int* offs = (int*)w;      w += sz_offs;
    int* cursor = (int*)w;    w += sz_cur;
    int* srcs = (int*)w;      w += sz_srcs;
    float* alpha = (float*)w; w += sz_alpha;
    float* out = (float*)d_out;

    hipMemsetAsync(count, 0, sz_count, stream);
    hist_kernel<<<512, 256, 0, stream>>>(ei, E, N, count);
    scan_kernel<<<1, 1024, 0, stream>>>(count, offs, cursor, N);
    scatter_kernel<<<512, 256, 0, stream>>>(ei, E, N, cursor, srcs);

    int nwb = (N + 3) / 4;
    dim3 ggrid((N + 63) / 64, 2);
    int ebl = (N * C + 255) / 256;

    const float* lin[3] = {x, h1, x};
    float* lout[3] = {h1, out, out};
    int laccum[3] = {0, 0, 1};

    for (int l = 0; l < 3; ++l) {
        wvec_kernel<<<H, 128, 0, stream>>>(Wl[l], asl[l], adl[l], vs, vd);
        al_kernel<<<nwb, 256, 0, stream>>>(lin[l], vs, vd, als, ald, N);
        alpha_kernel<<<nwb, 256, 0, stream>>>(als, ald, offs, srcs, alpha, N, ET);
        bias_kernel<<<ebl, 256, 0, stream>>>(lout[l], bl[l], N * C, laccum[l]);
        for (int h = 0; h < H; ++h) {
            gemm_kernel<<<ggrid, 256, 0, stream>>>(lin[l], Wl[l] + (size_t)h * C * C, xh, N);
            agg_kernel<<<nwb, 256, 0, stream>>>(xh, alpha + (size_t)h * ET, offs, srcs, lout[l], N);
        }
    }
}

// Round 4
// 528.033 us; speedup vs baseline: 1.8604x; 1.8604x over previous
//
#include <hip/hip_runtime.h>
#include <math.h>

#define C 128
#define H 4

typedef unsigned short u16;
typedef __attribute__((ext_vector_type(8))) short short8;
typedef __attribute__((ext_vector_type(4))) float f32x4;
typedef __attribute__((ext_vector_type(4))) u16 u16x4;

__device__ __forceinline__ float b2f(u16 u) {
    union { unsigned i; float f; } x; x.i = (unsigned)u << 16; return x.f;
}
__device__ __forceinline__ u16 f2b(float f) {
    union { float f; unsigned i; } x; x.f = f;
    unsigned r = x.i + 0x7FFFu + ((x.i >> 16) & 1u);
    return (u16)(r >> 16);
}
__device__ __forceinline__ float lrelu(float x) { return x > 0.f ? x : 0.2f * x; }

// ---------------- CSR build (edge_index arrives int32) ----------------

__global__ void hist_kernel(const int* __restrict__ ei, int E, int N,
                            int* __restrict__ count) {
    int total = E + N;
    for (int e = blockIdx.x * blockDim.x + threadIdx.x; e < total;
         e += gridDim.x * blockDim.x) {
        int d = (e < E) ? ei[E + e] : (e - E);
        if ((unsigned)d < (unsigned)N) atomicAdd(&count[d], 1);
    }
}

__global__ __launch_bounds__(1024) void scan_kernel(const int* __restrict__ count,
                                                    int* __restrict__ offs,
                                                    int* __restrict__ cursor, int N) {
    const int T = 1024;
    int tid = threadIdx.x;
    int CH = (N + T - 1) / T;
    int base = tid * CH;
    int s = 0;
    for (int j = 0; j < CH; ++j) {
        int i = base + j;
        if (i < N) s += count[i];
    }
    __shared__ int part[T];
    part[tid] = s;
    __syncthreads();
    for (int off = 1; off < T; off <<= 1) {
        int v = (tid >= off) ? part[tid - off] : 0;
        __syncthreads();
        part[tid] += v;
        __syncthreads();
    }
    int run = (tid == 0) ? 0 : part[tid - 1];
    for (int j = 0; j < CH; ++j) {
        int i = base + j;
        if (i < N) {
            offs[i] = run;
            cursor[i] = run;
            run += count[i];
        }
    }
    if (tid == T - 1) offs[N] = part[T - 1];
}

__global__ void scatter_kernel(const int* __restrict__ ei, int E, int N,
                               int* __restrict__ cursor, int* __restrict__ srcs) {
    int total = E + N;
    for (int e = blockIdx.x * blockDim.x + threadIdx.x; e < total;
         e += gridDim.x * blockDim.x) {
        int sNode, d;
        if (e < E) { sNode = ei[e]; d = ei[E + e]; }
        else       { sNode = e - E; d = sNode; }
        if ((unsigned)d < (unsigned)N && (unsigned)sNode < (unsigned)N) {
            int pos = atomicAdd(&cursor[d], 1);
            srcs[pos] = sNode;
        }
    }
}

// ---------------- fp32 -> bf16 convert ----------------

__global__ __launch_bounds__(256) void cvt_x_kernel(const float* __restrict__ x,
                                                    u16* __restrict__ xb, int total4) {
    int i = blockIdx.x * blockDim.x + threadIdx.x;
    if (i < total4) {
        float4 v = ((const float4*)x)[i];
        u16x4 o = {f2b(v.x), f2b(v.y), f2b(v.z), f2b(v.w)};
        ((u16x4*)xb)[i] = o;
    }
}

// W[h][i][o] fp32 -> Wt[h*128+o][i] bf16 (transpose to col-major per head)
__global__ __launch_bounds__(128) void cvt_w_kernel(const float* __restrict__ W,
                                                    u16* __restrict__ Wt) {
    int ho = blockIdx.x;          // 0..511 = h*128 + o
    int h = ho >> 7, o = ho & 127;
    int i = threadIdx.x;
    Wt[(size_t)ho * C + i] = f2b(W[((size_t)h * C + i) * C + o]);
}

// ---------------- W@a vectors (fp32) ----------------

__global__ __launch_bounds__(128) void wvec_kernel(const float* __restrict__ W,
                                                   const float* __restrict__ av_s,
                                                   const float* __restrict__ av_d,
                                                   float* __restrict__ vs,
                                                   float* __restrict__ vd) {
    int h = blockIdx.x;
    int i = threadIdx.x;
    const float* Wr = W + ((size_t)h * C + i) * C;
    float s = 0.f, d = 0.f;
    for (int o = 0; o < C; ++o) {
        float w = Wr[o];
        s += w * av_s[h * C + o];
        d += w * av_d[h * C + o];
    }
    vs[h * C + i] = s;
    vd[h * C + i] = d;
}

// ---------------- attention scalars from bf16 input ----------------

__global__ __launch_bounds__(256) void al_kernel(const u16* __restrict__ in,
                                                 const float* __restrict__ vs,
                                                 const float* __restrict__ vd,
                                                 float* __restrict__ als,
                                                 float* __restrict__ ald, int N) {
    int node = blockIdx.x * 4 + (threadIdx.x >> 6);
    int lane = threadIdx.x & 63;
    if (node >= N) return;
    float x0 = b2f(in[(size_t)node * C + lane]);
    float x1 = b2f(in[(size_t)node * C + 64 + lane]);
    #pragma unroll
    for (int h = 0; h < H; ++h) {
        float ps = x0 * vs[h * C + lane] + x1 * vs[h * C + 64 + lane];
        float pd = x0 * vd[h * C + lane] + x1 * vd[h * C + 64 + lane];
        #pragma unroll
        for (int m = 32; m; m >>= 1) {
            ps += __shfl_xor(ps, m);
            pd += __shfl_xor(pd, m);
        }
        if (lane == 0) {
            als[node * H + h] = ps;
            ald[node * H + h] = pd;
        }
    }
}

// ---------------- per-dst softmax stats: mx[n][h], invdn[n][h] ----------------

__global__ __launch_bounds__(256) void softmax_kernel(const float* __restrict__ als,
                                                      const float* __restrict__ ald,
                                                      const int* __restrict__ offs,
                                                      const int* __restrict__ srcs,
                                                      float* __restrict__ mx,
                                                      float* __restrict__ invdn, int N) {
    int node = blockIdx.x * 4 + (threadIdx.x >> 6);
    int lane = threadIdx.x & 63;
    if (node >= N) return;
    int beg = offs[node], end = offs[node + 1];
    float ad0 = ald[node * H + 0];
    float ad1 = ald[node * H + 1];
    float ad2 = ald[node * H + 2];
    float ad3 = ald[node * H + 3];

    float mx0 = -INFINITY, mx1 = -INFINITY, mx2 = -INFINITY, mx3 = -INFINITY;
    for (int i = beg + lane; i < end; i += 64) {
        int s = srcs[i];
        const float* ar = &als[s * H];
        mx0 = fmaxf(mx0, lrelu(ar[0] + ad0));
        mx1 = fmaxf(mx1, lrelu(ar[1] + ad1));
        mx2 = fmaxf(mx2, lrelu(ar[2] + ad2));
        mx3 = fmaxf(mx3, lrelu(ar[3] + ad3));
    }
    #pragma unroll
    for (int m = 32; m; m >>= 1) {
        mx0 = fmaxf(mx0, __shfl_xor(mx0, m));
        mx1 = fmaxf(mx1, __shfl_xor(mx1, m));
        mx2 = fmaxf(mx2, __shfl_xor(mx2, m));
        mx3 = fmaxf(mx3, __shfl_xor(mx3, m));
    }
    float dn0 = 0.f, dn1 = 0.f, dn2 = 0.f, dn3 = 0.f;
    for (int i = beg + lane; i < end; i += 64) {
        int s = srcs[i];
        const float* ar = &als[s * H];
        dn0 += expf(lrelu(ar[0] + ad0) - mx0);
        dn1 += expf(lrelu(ar[1] + ad1) - mx1);
        dn2 += expf(lrelu(ar[2] + ad2) - mx2);
        dn3 += expf(lrelu(ar[3] + ad3) - mx3);
    }
    #pragma unroll
    for (int m = 32; m; m >>= 1) {
        dn0 += __shfl_xor(dn0, m);
        dn1 += __shfl_xor(dn1, m);
        dn2 += __shfl_xor(dn2, m);
        dn3 += __shfl_xor(dn3, m);
    }
    if (lane == 0) {
        mx[node * H + 0] = mx0; invdn[node * H + 0] = 1.f / dn0;
        mx[node * H + 1] = mx1; invdn[node * H + 1] = 1.f / dn1;
        mx[node * H + 2] = mx2; invdn[node * H + 2] = 1.f / dn2;
        mx[node * H + 3] = mx3; invdn[node * H + 3] = 1.f / dn3;
    }
}

// ---------------- MFMA GEMM: xh[n][512] (bf16) = xb[n][128] @ Wt^T ----------------
// Wt layout: [512 out-cols][128 k], so B-frag (col, k0..k0+7) is 16B contiguous.

__global__ __launch_bounds__(256) void gemm_kernel(const u16* __restrict__ xb,
                                                   const u16* __restrict__ Wt,
                                                   u16* __restrict__ xh, int N) {
    int wave = threadIdx.x >> 6, lane = threadIdx.x & 63;
    int rowBase = blockIdx.x * 64 + wave * 16;
    int colBase = blockIdx.y * 64;
    int r = rowBase + (lane & 15);
    int rl = r < N ? r : N - 1;                 // clamp for loads; stores guarded
    int kg = (lane >> 4) * 8;                   // k offset within 32-chunk

    const short8* ap = (const short8*)(xb + (size_t)rl * C + kg);
    short8 a0 = ap[0], a1 = ap[4], a2 = ap[8], a3 = ap[12];  // k += 32 each

    f32x4 acc[4];
    #pragma unroll
    for (int t = 0; t < 4; ++t) acc[t] = (f32x4){0.f, 0.f, 0.f, 0.f};

    #pragma unroll
    for (int t = 0; t < 4; ++t) {
        int col = colBase + t * 16 + (lane & 15);
        const short8* bp = (const short8*)(Wt + (size_t)col * C + kg);
        acc[t] = __builtin_amdgcn_mfma_f32_16x16x32_bf16(a0, bp[0], acc[t], 0, 0, 0);
        acc[t] = __builtin_amdgcn_mfma_f32_16x16x32_bf16(a1, bp[4], acc[t], 0, 0, 0);
        acc[t] = __builtin_amdgcn_mfma_f32_16x16x32_bf16(a2, bp[8], acc[t], 0, 0, 0);
        acc[t] = __builtin_amdgcn_mfma_f32_16x16x32_bf16(a3, bp[12], acc[t], 0, 0, 0);
    }

    int prow = rowBase + (lane >> 4) * 4;       // D: col=lane&15, row=(lane>>4)*4+j
    #pragma unroll
    for (int t = 0; t < 4; ++t) {
        int col = colBase + t * 16 + (lane & 15);
        #pragma unroll
        for (int j = 0; j < 4; ++j) {
            int rr = prow + j;
            if (rr < N) xh[(size_t)rr * 512 + col] = f2b(acc[t][j]);
        }
    }
}

// ---------------- fused 4-head aggregation ----------------
// lane = head(lane>>4) x slot(lane&15); each lane accumulates 8 channels of one head.
// mode 0: write bf16 (h1); mode 1: write f32; mode 2: accumulate f32.

__global__ __launch_bounds__(256) void agg_kernel(const u16* __restrict__ xh,
                                                  const float* __restrict__ als,
                                                  const float* __restrict__ ald,
                                                  const float* __restrict__ mx,
                                                  const float* __restrict__ invdn,
                                                  const int* __restrict__ offs,
                                                  const int* __restrict__ srcs,
                                                  const float* __restrict__ bias,
                                                  u16* __restrict__ outb,
                                                  float* __restrict__ outf,
                                                  int N, int mode) {
    int node = blockIdx.x * 4 + (threadIdx.x >> 6);
    int lane = threadIdx.x & 63;
    if (node >= N) return;
    int hg = lane >> 4, sl = lane & 15;
    int beg = offs[node], end = offs[node + 1];
    float adh = ald[node * H + hg];
    float mh = mx[node * H + hg];
    float ivh = invdn[node * H + hg];

    float acc[8] = {0.f, 0.f, 0.f, 0.f, 0.f, 0.f, 0.f, 0.f};
    for (int i = beg; i < end; ++i) {
        int s = srcs[i];
        float w = expf(lrelu(als[s * H + hg] + adh) - mh) * ivh;
        short8 v = *(const short8*)(xh + (size_t)s * 512 + lane * 8);
        #pragma unroll
        for (int j = 0; j < 8; ++j) acc[j] += w * b2f((u16)v[j]);
    }
    #pragma unroll
    for (int j = 0; j < 8; ++j) {
        acc[j] += __shfl_xor(acc[j], 16);
        acc[j] += __shfl_xor(acc[j], 32);
    }
    if (lane < 16) {
        size_t base = (size_t)node * C + sl * 8;
        #pragma unroll
        for (int j = 0; j < 8; ++j) {
            float v = 0.25f * acc[j] + bias[sl * 8 + j];
            if (mode == 0) outb[base + j] = f2b(v);
            else if (mode == 1) outf[base + j] = v;
            else outf[base + j] += v;
        }
    }
}

// ---------------- launch ----------------

extern "C" void kernel_launch(void* const* d_in, const int* in_sizes, int n_in,
                              void* d_out, int out_size, void* d_ws, size_t ws_size,
                              hipStream_t stream) {
    const float* x = (const float*)d_in[0];
    const int* ei = (const int*)d_in[1];
    const float* Wl[3]  = {(const float*)d_in[2], (const float*)d_in[6], (const float*)d_in[10]};
    const float* asl[3] = {(const float*)d_in[3], (const float*)d_in[7], (const float*)d_in[11]};
    const float* adl[3] = {(const float*)d_in[4], (const float*)d_in[8], (const float*)d_in[12]};
    const float* bl[3]  = {(const float*)d_in[5], (const float*)d_in[9], (const float*)d_in[13]};

    int N = in_sizes[0] / C;   // 20000
    int E = in_sizes[1] / 2;   // 320000
    int ET = E + N;

    size_t sz_xb    = (size_t)N * C * 2;
    size_t sz_h1b   = (size_t)N * C * 2;
    size_t sz_xh    = (size_t)N * 512 * 2;
    size_t sz_wt    = (size_t)512 * C * 2;
    size_t sz_v     = (size_t)H * C * 4;
    size_t sz_nh    = (size_t)N * H * 4;
    size_t sz_count = (size_t)N * 4;
    size_t sz_offs  = (size_t)(N + 4) * 4;
    size_t sz_srcs  = (size_t)ET * 4;
    size_t required = sz_xb + sz_h1b + sz_xh + sz_wt + 2 * sz_v + 4 * sz_nh +
                      2 * sz_count + sz_offs + sz_srcs;
    if (ws_size < required) return;

    char* w = (char*)d_ws;
    u16* xb = (u16*)w;       w += sz_xb;
    u16* h1b = (u16*)w;      w += sz_h1b;
    u16* xh = (u16*)w;       w += sz_xh;
    u16* Wt = (u16*)w;       w += sz_wt;
    float* vs = (float*)w;   w += sz_v;
    float* vd = (float*)w;   w += sz_v;
    float* als = (float*)w;  w += sz_nh;
    float* ald = (float*)w;  w += sz_nh;
    float* mx = (float*)w;   w += sz_nh;
    float* invdn = (float*)w;w += sz_nh;
    int* count = (int*)w;    w += sz_count;
    int* cursor = (int*)w;   w += sz_count;
    int* offs = (int*)w;     w += sz_offs;
    int* srcs = (int*)w;     w += sz_srcs;
    float* out = (float*)d_out;

    hipMemsetAsync(count, 0, sz_count, stream);
    hist_kernel<<<512, 256, 0, stream>>>(ei, E, N, count);
    scan_kernel<<<1, 1024, 0, stream>>>(count, offs, cursor, N);
    scatter_kernel<<<512, 256, 0, stream>>>(ei, E, N, cursor, srcs);

    int total4 = (N * C) / 4;
    cvt_x_kernel<<<(total4 + 255) / 256, 256, 0, stream>>>(x, xb, total4);

    int nwb = (N + 3) / 4;
    dim3 ggrid((N + 63) / 64, 8);

    const u16* lin[3] = {xb, h1b, xb};
    int lmode[3] = {0, 1, 2};

    for (int l = 0; l < 3; ++l) {
        wvec_kernel<<<H, 128, 0, stream>>>(Wl[l], asl[l], adl[l], vs, vd);
        al_kernel<<<nwb, 256, 0, stream>>>(lin[l], vs, vd, als, ald, N);
        softmax_kernel<<<nwb, 256, 0, stream>>>(als, ald, offs, srcs, mx, invdn, N);
        cvt_w_kernel<<<512, 128, 0, stream>>>(Wl[l], Wt);
        gemm_kernel<<<ggrid, 256, 0, stream>>>(lin[l], Wt, xh, N);
        agg_kernel<<<nwb, 256, 0, stream>>>(xh, als, ald, mx, invdn, offs, srcs,
                                            bl[l], h1b, out, N, lmode[l]);
    }
}

// Round 5
// 435.216 us; speedup vs baseline: 2.2572x; 1.2133x over previous
//
#include <hip/hip_runtime.h>
#include <math.h>

#define C 128

typedef unsigned short u16;
typedef __attribute__((ext_vector_type(8))) short short8;
typedef __attribute__((ext_vector_type(4))) float f32x4;
typedef __attribute__((ext_vector_type(4))) u16 u16x4;

__device__ __forceinline__ float b2f(u16 u) {
    union { unsigned i; float f; } x; x.i = (unsigned)u << 16; return x.f;
}
__device__ __forceinline__ u16 f2b(float f) {
    union { float f; unsigned i; } x; x.f = f;
    unsigned r = x.i + 0x7FFFu + ((x.i >> 16) & 1u);
    return (u16)(r >> 16);
}
__device__ __forceinline__ float lrelu(float x) { return x > 0.f ? x : 0.2f * x; }

// ---------------- CSR build (edge_index arrives int32) ----------------

__global__ void hist_kernel(const int* __restrict__ ei, int E, int N,
                            int* __restrict__ count) {
    int total = E + N;
    for (int e = blockIdx.x * blockDim.x + threadIdx.x; e < total;
         e += gridDim.x * blockDim.x) {
        int d = (e < E) ? ei[E + e] : (e - E);
        if ((unsigned)d < (unsigned)N) atomicAdd(&count[d], 1);
    }
}

__global__ __launch_bounds__(1024) void scan_kernel(const int* __restrict__ count,
                                                    int* __restrict__ offs,
                                                    int* __restrict__ cursor, int N) {
    const int T = 1024;
    int tid = threadIdx.x;
    int CH = (N + T - 1) / T;
    int base = tid * CH;
    int s = 0;
    for (int j = 0; j < CH; ++j) {
        int i = base + j;
        if (i < N) s += count[i];
    }
    __shared__ int part[T];
    part[tid] = s;
    __syncthreads();
    for (int off = 1; off < T; off <<= 1) {
        int v = (tid >= off) ? part[tid - off] : 0;
        __syncthreads();
        part[tid] += v;
        __syncthreads();
    }
    int run = (tid == 0) ? 0 : part[tid - 1];
    for (int j = 0; j < CH; ++j) {
        int i = base + j;
        if (i < N) {
            offs[i] = run;
            cursor[i] = run;
            run += count[i];
        }
    }
    if (tid == T - 1) offs[N] = part[T - 1];
}

__global__ void scatter_kernel(const int* __restrict__ ei, int E, int N,
                               int* __restrict__ cursor, int* __restrict__ srcs) {
    int total = E + N;
    for (int e = blockIdx.x * blockDim.x + threadIdx.x; e < total;
         e += gridDim.x * blockDim.x) {
        int sNode, d;
        if (e < E) { sNode = ei[e]; d = ei[E + e]; }
        else       { sNode = e - E; d = sNode; }
        if ((unsigned)d < (unsigned)N && (unsigned)sNode < (unsigned)N) {
            int pos = atomicAdd(&cursor[d], 1);
            srcs[pos] = sNode;
        }
    }
}

// ---------------- fp32 -> bf16 ----------------

__global__ __launch_bounds__(256) void cvt_x_kernel(const float* __restrict__ x,
                                                    u16* __restrict__ xb, int total4) {
    int i = blockIdx.x * blockDim.x + threadIdx.x;
    if (i < total4) {
        float4 v = ((const float4*)x)[i];
        u16x4 o = {f2b(v.x), f2b(v.y), f2b(v.z), f2b(v.w)};
        ((u16x4*)xb)[i] = o;
    }
}

// Wt[col][k] bf16; col = slot*128 + o; slot<4 -> Wa head slot, slot>=4 -> Wb head slot-4
__global__ __launch_bounds__(128) void cvt_w_kernel(const float* __restrict__ Wa,
                                                    const float* __restrict__ Wb,
                                                    u16* __restrict__ Wt) {
    int col = blockIdx.x;
    int slot = col >> 7, o = col & 127;
    const float* W = (slot < 4) ? Wa : Wb;
    int h = slot & 3;
    int i = threadIdx.x;
    Wt[(size_t)col * C + i] = f2b(W[((size_t)h * C + i) * C + o]);
}

// ---------------- W@a vectors: vs/vd[slot][i] ----------------
// grid (nslots, 4), 256 thr; wave handles 8 rows.

__global__ __launch_bounds__(256) void wvec_kernel(const float* __restrict__ Wa,
                                                   const float* __restrict__ asa,
                                                   const float* __restrict__ ada,
                                                   const float* __restrict__ Wb,
                                                   const float* __restrict__ asb,
                                                   const float* __restrict__ adb,
                                                   float* __restrict__ vs,
                                                   float* __restrict__ vd) {
    int slot = blockIdx.x;
    const float* W  = (slot < 4) ? Wa : Wb;
    const float* s_ = (slot < 4) ? asa : asb;
    const float* d_ = (slot < 4) ? ada : adb;
    int h = slot & 3;
    int wave = threadIdx.x >> 6, lane = threadIdx.x & 63;
    int rbase = blockIdx.y * 32 + wave * 8;
    float as0 = s_[h * C + lane], as1 = s_[h * C + 64 + lane];
    float ad0 = d_[h * C + lane], ad1 = d_[h * C + 64 + lane];
    #pragma unroll
    for (int j = 0; j < 8; ++j) {
        int i = rbase + j;
        const float* Wr = W + ((size_t)h * C + i) * C;
        float w0 = Wr[lane], w1 = Wr[64 + lane];
        float ps = w0 * as0 + w1 * as1;
        float pd = w0 * ad0 + w1 * ad1;
        #pragma unroll
        for (int m = 32; m; m >>= 1) {
            ps += __shfl_xor(ps, m);
            pd += __shfl_xor(pd, m);
        }
        if (lane == 0) { vs[slot * C + i] = ps; vd[slot * C + i] = pd; }
    }
}

// ---------------- attention scalars: als/ald [N][NH] ----------------

template <int NH>
__global__ __launch_bounds__(256) void al_kernel(const u16* __restrict__ in,
                                                 const float* __restrict__ vs,
                                                 const float* __restrict__ vd,
                                                 float* __restrict__ als,
                                                 float* __restrict__ ald, int N) {
    int node = blockIdx.x * 4 + (threadIdx.x >> 6);
    int lane = threadIdx.x & 63;
    if (node >= N) return;
    float x0 = b2f(in[(size_t)node * C + lane]);
    float x1 = b2f(in[(size_t)node * C + 64 + lane]);
    #pragma unroll
    for (int h = 0; h < NH; ++h) {
        float ps = x0 * vs[h * C + lane] + x1 * vs[h * C + 64 + lane];
        float pd = x0 * vd[h * C + lane] + x1 * vd[h * C + 64 + lane];
        #pragma unroll
        for (int m = 32; m; m >>= 1) {
            ps += __shfl_xor(ps, m);
            pd += __shfl_xor(pd, m);
        }
        if (lane == 0) { als[node * NH + h] = ps; ald[node * NH + h] = pd; }
    }
}

// ---------------- MFMA GEMM: xh[n][ncols] bf16 = xb[n][128] @ Wt^T ----------------

__global__ __launch_bounds__(256) void gemm_kernel(const u16* __restrict__ xb,
                                                   const u16* __restrict__ Wt,
                                                   u16* __restrict__ xh, int N,
                                                   int ncols) {
    int wave = threadIdx.x >> 6, lane = threadIdx.x & 63;
    int rowBase = blockIdx.x * 64 + wave * 16;
    int colBase = blockIdx.y * 64;
    int r = rowBase + (lane & 15);
    int rl = r < N ? r : N - 1;
    int kg = (lane >> 4) * 8;

    const short8* ap = (const short8*)(xb + (size_t)rl * C + kg);
    short8 a0 = ap[0], a1 = ap[4], a2 = ap[8], a3 = ap[12];

    f32x4 acc[4];
    #pragma unroll
    for (int t = 0; t < 4; ++t) acc[t] = (f32x4){0.f, 0.f, 0.f, 0.f};

    #pragma unroll
    for (int t = 0; t < 4; ++t) {
        int col = colBase + t * 16 + (lane & 15);
        const short8* bp = (const short8*)(Wt + (size_t)col * C + kg);
        acc[t] = __builtin_amdgcn_mfma_f32_16x16x32_bf16(a0, bp[0], acc[t], 0, 0, 0);
        acc[t] = __builtin_amdgcn_mfma_f32_16x16x32_bf16(a1, bp[4], acc[t], 0, 0, 0);
        acc[t] = __builtin_amdgcn_mfma_f32_16x16x32_bf16(a2, bp[8], acc[t], 0, 0, 0);
        acc[t] = __builtin_amdgcn_mfma_f32_16x16x32_bf16(a3, bp[12], acc[t], 0, 0, 0);
    }

    int prow = rowBase + (lane >> 4) * 4;
    #pragma unroll
    for (int t = 0; t < 4; ++t) {
        int col = colBase + t * 16 + (lane & 15);
        #pragma unroll
        for (int j = 0; j < 4; ++j) {
            int rr = prow + j;
            if (rr < N) xh[(size_t)rr * ncols + col] = f2b(acc[t][j]);
        }
    }
}

// ---------------- fused agg: layer1 (cols 0-511 -> h1 bf16) + residual (cols 512-1023 -> out f32) ----
// Softmax denominators computed in-kernel (no max subtraction; logits are O(few), fp32-safe).

__global__ __launch_bounds__(256) void agg_fused_kernel(const u16* __restrict__ xh,
                                                        const float* __restrict__ als,
                                                        const float* __restrict__ ald,
                                                        const int* __restrict__ offs,
                                                        const int* __restrict__ srcs,
                                                        const float* __restrict__ b1,
                                                        const float* __restrict__ br,
                                                        u16* __restrict__ h1b,
                                                        float* __restrict__ out, int N) {
    int node = blockIdx.x * 4 + (threadIdx.x >> 6);
    int lane = threadIdx.x & 63;
    if (node >= N) return;
    int hg = lane >> 4, sl = lane & 15;
    int beg = offs[node], end = offs[node + 1];
    float adl = ald[node * 8 + hg];
    float adr = ald[node * 8 + 4 + hg];

    // phase 1: per-head denominators (16-lane-group strided)
    float dnl = 0.f, dnr = 0.f;
    for (int i = beg + sl; i < end; i += 16) {
        int s = srcs[i];
        dnl += __expf(lrelu(als[s * 8 + hg] + adl));
        dnr += __expf(lrelu(als[s * 8 + 4 + hg] + adr));
    }
    #pragma unroll
    for (int m = 1; m < 16; m <<= 1) {
        dnl += __shfl_xor(dnl, m);
        dnr += __shfl_xor(dnr, m);
    }
    float il = 1.f / dnl, ir = 1.f / dnr;

    // phase 2: weighted gather, 2-edge unrolled
    float acl[8] = {0.f, 0.f, 0.f, 0.f, 0.f, 0.f, 0.f, 0.f};
    float acr[8] = {0.f, 0.f, 0.f, 0.f, 0.f, 0.f, 0.f, 0.f};
    int i = beg;
    for (; i + 2 <= end; i += 2) {
        int s0 = srcs[i], s1 = srcs[i + 1];
        float w10 = __expf(lrelu(als[s0 * 8 + hg] + adl)) * il;
        float wr0 = __expf(lrelu(als[s0 * 8 + 4 + hg] + adr)) * ir;
        float w11 = __expf(lrelu(als[s1 * 8 + hg] + adl)) * il;
        float wr1 = __expf(lrelu(als[s1 * 8 + 4 + hg] + adr)) * ir;
        short8 v10 = *(const short8*)(xh + (size_t)s0 * 1024 + lane * 8);
        short8 vr0 = *(const short8*)(xh + (size_t)s0 * 1024 + 512 + lane * 8);
        short8 v11 = *(const short8*)(xh + (size_t)s1 * 1024 + lane * 8);
        short8 vr1 = *(const short8*)(xh + (size_t)s1 * 1024 + 512 + lane * 8);
        #pragma unroll
        for (int j = 0; j < 8; ++j) {
            acl[j] += w10 * b2f((u16)v10[j]) + w11 * b2f((u16)v11[j]);
            acr[j] += wr0 * b2f((u16)vr0[j]) + wr1 * b2f((u16)vr1[j]);
        }
    }
    if (i < end) {
        int s0 = srcs[i];
        float w10 = __expf(lrelu(als[s0 * 8 + hg] + adl)) * il;
        float wr0 = __expf(lrelu(als[s0 * 8 + 4 + hg] + adr)) * ir;
        short8 v10 = *(const short8*)(xh + (size_t)s0 * 1024 + lane * 8);
        short8 vr0 = *(const short8*)(xh + (size_t)s0 * 1024 + 512 + lane * 8);
        #pragma unroll
        for (int j = 0; j < 8; ++j) {
            acl[j] += w10 * b2f((u16)v10[j]);
            acr[j] += wr0 * b2f((u16)vr0[j]);
        }
    }
    #pragma unroll
    for (int j = 0; j < 8; ++j) {
        acl[j] += __shfl_xor(acl[j], 16);
        acl[j] += __shfl_xor(acl[j], 32);
        acr[j] += __shfl_xor(acr[j], 16);
        acr[j] += __shfl_xor(acr[j], 32);
    }
    if (lane < 16) {
        size_t base = (size_t)node * C + sl * 8;
        #pragma unroll
        for (int j = 0; j < 8; ++j) {
            h1b[base + j] = f2b(0.25f * acl[j] + b1[sl * 8 + j]);
            out[base + j] = 0.25f * acr[j] + br[sl * 8 + j];
        }
    }
}

// ---------------- layer-2 agg: out += mean_h sum alpha*xh[src] + b2 ----------------

__global__ __launch_bounds__(256) void agg_single_kernel(const u16* __restrict__ xh,
                                                         const float* __restrict__ als,
                                                         const float* __restrict__ ald,
                                                         const int* __restrict__ offs,
                                                         const int* __restrict__ srcs,
                                                         const float* __restrict__ b2,
                                                         float* __restrict__ out, int N) {
    int node = blockIdx.x * 4 + (threadIdx.x >> 6);
    int lane = threadIdx.x & 63;
    if (node >= N) return;
    int hg = lane >> 4, sl = lane & 15;
    int beg = offs[node], end = offs[node + 1];
    float adh = ald[node * 4 + hg];

    float dn = 0.f;
    for (int i = beg + sl; i < end; i += 16) {
        dn += __expf(lrelu(als[srcs[i] * 4 + hg] + adh));
    }
    #pragma unroll
    for (int m = 1; m < 16; m <<= 1) dn += __shfl_xor(dn, m);
    float inv = 1.f / dn;

    float ac[8] = {0.f, 0.f, 0.f, 0.f, 0.f, 0.f, 0.f, 0.f};
    int i = beg;
    for (; i + 2 <= end; i += 2) {
        int s0 = srcs[i], s1 = srcs[i + 1];
        float w0 = __expf(lrelu(als[s0 * 4 + hg] + adh)) * inv;
        float w1 = __expf(lrelu(als[s1 * 4 + hg] + adh)) * inv;
        short8 v0 = *(const short8*)(xh + (size_t)s0 * 512 + lane * 8);
        short8 v1 = *(const short8*)(xh + (size_t)s1 * 512 + lane * 8);
        #pragma unroll
        for (int j = 0; j < 8; ++j) {
            ac[j] += w0 * b2f((u16)v0[j]) + w1 * b2f((u16)v1[j]);
        }
    }
    if (i < end) {
        int s0 = srcs[i];
        float w0 = __expf(lrelu(als[s0 * 4 + hg] + adh)) * inv;
        short8 v0 = *(const short8*)(xh + (size_t)s0 * 512 + lane * 8);
        #pragma unroll
        for (int j = 0; j < 8; ++j) ac[j] += w0 * b2f((u16)v0[j]);
    }
    #pragma unroll
    for (int j = 0; j < 8; ++j) {
        ac[j] += __shfl_xor(ac[j], 16);
        ac[j] += __shfl_xor(ac[j], 32);
    }
    if (lane < 16) {
        size_t base = (size_t)node * C + sl * 8;
        #pragma unroll
        for (int j = 0; j < 8; ++j) out[base + j] += 0.25f * ac[j] + b2[sl * 8 + j];
    }
}

// ---------------- launch ----------------

extern "C" void kernel_launch(void* const* d_in, const int* in_sizes, int n_in,
                              void* d_out, int out_size, void* d_ws, size_t ws_size,
                              hipStream_t stream) {
    const float* x = (const float*)d_in[0];
    const int* ei = (const int*)d_in[1];
    const float* W1 = (const float*)d_in[2];
    const float* as1 = (const float*)d_in[3];
    const float* ad1 = (const float*)d_in[4];
    const float* b1 = (const float*)d_in[5];
    const float* W2 = (const float*)d_in[6];
    const float* as2 = (const float*)d_in[7];
    const float* ad2 = (const float*)d_in[8];
    const float* b2 = (const float*)d_in[9];
    const float* Wr = (const float*)d_in[10];
    const float* asr = (const float*)d_in[11];
    const float* adr = (const float*)d_in[12];
    const float* br = (const float*)d_in[13];

    int N = in_sizes[0] / C;   // 20000
    int E = in_sizes[1] / 2;   // 320000
    int ET = E + N;

    size_t sz_xb    = (size_t)N * C * 2;
    size_t sz_h1b   = (size_t)N * C * 2;
    size_t sz_xh    = (size_t)N * 1024 * 2;
    size_t sz_wt    = (size_t)1024 * C * 2;
    size_t sz_v     = (size_t)8 * C * 4;
    size_t sz_nh    = (size_t)N * 8 * 4;
    size_t sz_count = (size_t)N * 4;
    size_t sz_offs  = (size_t)(N + 4) * 4;
    size_t sz_srcs  = (size_t)ET * 4;
    size_t required = sz_xb + sz_h1b + sz_xh + sz_wt + 2 * sz_v + 2 * sz_nh +
                      2 * sz_count + sz_offs + sz_srcs;
    if (ws_size < required) return;

    char* w = (char*)d_ws;
    u16* xb = (u16*)w;        w += sz_xb;
    u16* h1b = (u16*)w;       w += sz_h1b;
    u16* xh = (u16*)w;        w += sz_xh;
    u16* Wt = (u16*)w;        w += sz_wt;
    float* vs = (float*)w;    w += sz_v;
    float* vd = (float*)w;    w += sz_v;
    float* als = (float*)w;   w += sz_nh;
    float* ald = (float*)w;   w += sz_nh;
    int* count = (int*)w;     w += sz_count;
    int* cursor = (int*)w;    w += sz_count;
    int* offs = (int*)w;      w += sz_offs;
    int* srcs = (int*)w;      w += sz_srcs;
    float* out = (float*)d_out;

    hipMemsetAsync(count, 0, sz_count, stream);
    hist_kernel<<<512, 256, 0, stream>>>(ei, E, N, count);
    scan_kernel<<<1, 1024, 0, stream>>>(count, offs, cursor, N);
    scatter_kernel<<<512, 256, 0, stream>>>(ei, E, N, cursor, srcs);

    int total4 = (N * C) / 4;
    cvt_x_kernel<<<(total4 + 255) / 256, 256, 0, stream>>>(x, xb, total4);

    int nwb = (N + 3) / 4;
    int gx = (N + 63) / 64;

    // group A: layer1 + residual (slots 0-3 = W1, 4-7 = Wr)
    wvec_kernel<<<dim3(8, 4), 256, 0, stream>>>(W1, as1, ad1, Wr, asr, adr, vs, vd);
    cvt_w_kernel<<<1024, 128, 0, stream>>>(W1, Wr, Wt);
    al_kernel<8><<<nwb, 256, 0, stream>>>(xb, vs, vd, als, ald, N);
    gemm_kernel<<<dim3(gx, 16), 256, 0, stream>>>(xb, Wt, xh, N, 1024);
    agg_fused_kernel<<<nwb, 256, 0, stream>>>(xh, als, ald, offs, srcs, b1, br,
                                              h1b, out, N);

    // group B: layer2 (slots 0-3 = W2)
    wvec_kernel<<<dim3(4, 4), 256, 0, stream>>>(W2, as2, ad2, W2, as2, ad2, vs, vd);
    cvt_w_kernel<<<512, 128, 0, stream>>>(W2, W2, Wt);
    al_kernel<4><<<nwb, 256, 0, stream>>>(h1b, vs, vd, als, ald, N);
    gemm_kernel<<<dim3(gx, 8), 256, 0, stream>>>(h1b, Wt, xh, N, 512);
    agg_single_kernel<<<nwb, 256, 0, stream>>>(xh, als, ald, offs, srcs, b2, out, N);
}